// Round 2
// baseline (6344.455 us; speedup 1.0000x reference)
//
#include <hip/hip_runtime.h>
#include <hip/hip_bf16.h>

#define B_ 2
#define S_ 2048
#define H_ 1024
#define NH_ 16
#define HD_ 64
#define M_ (B_*S_)   // 4096 rows

// ---------------- wave reductions (wave = 64 lanes) ----------------
__device__ inline float waveReduceMax(float v) {
#pragma unroll
  for (int off = 32; off >= 1; off >>= 1) v = fmaxf(v, __shfl_xor(v, off));
  return v;
}
__device__ inline float waveReduceSum(float v) {
#pragma unroll
  for (int off = 32; off >= 1; off >>= 1) v += __shfl_xor(v, off);
  return v;
}

// ---------------- GEMM: C[M,1024] = A[M,1024] @ W[1024,1024] + bias ----------------
// HEAD_IN:  A is stored [B,NH,S,HD] (ctx layout); logical (m,k) -> ((b*NH+h)*S+s)*64+d
// HEAD_OUT: C written to [B,NH,S,HD]
template<bool HEAD_IN, bool HEAD_OUT>
__global__ __launch_bounds__(256)
void gemm_bias(const float* __restrict__ A, const float* __restrict__ W,
               const float* __restrict__ bias, float* __restrict__ C) {
  const int K = H_, N = H_;
  __shared__ float As[64][20];  // padded; float4 stores stay 16B aligned (80B row)
  __shared__ float Bs[16][68];  // padded; 272B row

  const int tid = threadIdx.x;
  const int tx = tid & 15, ty = tid >> 4;
  const int m0 = blockIdx.y * 64, n0 = blockIdx.x * 64;

  // A-tile load mapping: 64 rows x 16 cols, 4 consecutive k per thread
  const int lr = tid >> 2;         // 0..63
  const int lk = (tid & 3) << 2;   // 0,4,8,12
  // B-tile load mapping: 16 rows x 64 cols
  const int bk = tid >> 4;         // 0..15
  const int bn = (tid & 15) << 2;  // 0..60

  float acc[4][4] = {};

  for (int k0 = 0; k0 < K; k0 += 16) {
    float4 av;
    if (!HEAD_IN) {
      av = *(const float4*)(A + (size_t)(m0 + lr) * K + (k0 + lk));
    } else {
      int m = m0 + lr, k = k0 + lk;
      int b = m >> 11, s = m & (S_ - 1);
      int h = k >> 6,  d = k & 63;
      av = *(const float4*)(A + (((size_t)(b * NH_ + h) * S_ + s) << 6) + d);
    }
    float4 bv = *(const float4*)(W + (size_t)(k0 + bk) * N + (n0 + bn));

    __syncthreads();
    *(float4*)&As[lr][lk] = av;
    *(float4*)&Bs[bk][bn] = bv;
    __syncthreads();

#pragma unroll
    for (int kk = 0; kk < 16; ++kk) {
      float a[4], b[4];
#pragma unroll
      for (int i = 0; i < 4; ++i) a[i] = As[4 * ty + i][kk];
#pragma unroll
      for (int j = 0; j < 4; ++j) b[j] = Bs[kk][4 * tx + j];
#pragma unroll
      for (int i = 0; i < 4; ++i)
#pragma unroll
        for (int j = 0; j < 4; ++j)
          acc[i][j] += a[i] * b[j];
    }
  }

#pragma unroll
  for (int i = 0; i < 4; ++i) {
    int m = m0 + 4 * ty + i;
#pragma unroll
    for (int j = 0; j < 4; ++j) {
      int n = n0 + 4 * tx + j;
      float v = acc[i][j] + bias[n];
      if (!HEAD_OUT) {
        C[(size_t)m * N + n] = v;
      } else {
        int b = m >> 11, s = m & (S_ - 1);
        int h = n >> 6,  d = n & 63;
        C[(((size_t)(b * NH_ + h) * S_ + s) << 6) + d] = v;
      }
    }
  }
}

// ---------------- Attention: one block (256 thr) per (b,h,q) row ----------------
// Q,K,V in [B*NH, S, 64]; ctx written in-place over Q (each block reads only its own Q row).
__global__ __launch_bounds__(256)
void attn_kernel(const float* __restrict__ Q, const float* __restrict__ Km,
                 const float* __restrict__ Vm, float* __restrict__ ctx) {
  __shared__ float q_s[64];
  __shared__ float sc[S_];
  __shared__ float redm[4], reds[4];
  __shared__ float part[4][64];

  const int tid = threadIdx.x;
  const int bhq = blockIdx.x;
  const int qi = bhq & (S_ - 1);
  const int bh = bhq >> 11;
  const float* qrow = Q + (((size_t)bh * S_ + qi) << 6);
  const float* Kb = Km + ((size_t)bh * S_ << 6);
  const float* Vb = Vm + ((size_t)bh * S_ << 6);

  if (tid < 64) q_s[tid] = qrow[tid];
  __syncthreads();

  // scores: each thread does 8 k-rows
  float ls[8];
  float lmax = -1e30f;
  const float4* q4 = (const float4*)q_s;
#pragma unroll
  for (int i = 0; i < 8; ++i) {
    int k = tid + (i << 8);
    const float4* kr = (const float4*)(Kb + ((size_t)k << 6));
    float acc = 0.f;
#pragma unroll
    for (int d = 0; d < 16; ++d) {
      float4 kv = kr[d], qv = q4[d];
      acc += qv.x * kv.x + qv.y * kv.y + qv.z * kv.z + qv.w * kv.w;
    }
    acc *= 0.125f;  // 1/sqrt(64)
    ls[i] = acc;
    lmax = fmaxf(lmax, acc);
  }
  const int lane = tid & 63, wave = tid >> 6;
  lmax = waveReduceMax(lmax);
  if (lane == 0) redm[wave] = lmax;
  __syncthreads();
  const float gmax = fmaxf(fmaxf(redm[0], redm[1]), fmaxf(redm[2], redm[3]));

  float lsum = 0.f;
#pragma unroll
  for (int i = 0; i < 8; ++i) {
    float p = __expf(ls[i] - gmax);
    sc[tid + (i << 8)] = p;
    lsum += p;
  }
  lsum = waveReduceSum(lsum);
  if (lane == 0) reds[wave] = lsum;
  __syncthreads();  // also publishes sc[]
  const float inv = 1.f / (reds[0] + reds[1] + reds[2] + reds[3]);

  // PV: wave c handles k in [c*512, (c+1)*512); lane d owns output dim d
  const int d = lane, c = wave;
  float acc = 0.f;
  const float* vcol = Vb + d;
#pragma unroll 8
  for (int k = c * 512; k < (c + 1) * 512; ++k)
    acc += sc[k] * vcol[(size_t)k << 6];
  part[c][d] = acc;
  __syncthreads();
  if (tid < 64) {
    float r = (part[0][tid] + part[1][tid] + part[2][tid] + part[3][tid]) * inv;
    ctx[(((size_t)bh * S_ + qi) << 6) + tid] = r;
  }
}

// ---------------- residual + LayerNorm: one block per row ----------------
__global__ __launch_bounds__(256)
void resid_ln(const float* __restrict__ attn_out, const float* __restrict__ hs,
              const float* __restrict__ gamma, const float* __restrict__ beta,
              float* __restrict__ out) {
  __shared__ float reds[4], reds2[4];
  const int row = blockIdx.x;
  const int tid = threadIdx.x;
  const float4* a4 = (const float4*)(attn_out + ((size_t)row << 10));
  const float4* h4 = (const float4*)(hs + ((size_t)row << 10));
  float4 a = a4[tid], h = h4[tid];
  float e0 = a.x + h.x, e1 = a.y + h.y, e2 = a.z + h.z, e3 = a.w + h.w;
  float s  = e0 + e1 + e2 + e3;
  float sq = e0 * e0 + e1 * e1 + e2 * e2 + e3 * e3;
  s = waveReduceSum(s);
  sq = waveReduceSum(sq);
  const int lane = tid & 63, wave = tid >> 6;
  if (lane == 0) { reds[wave] = s; reds2[wave] = sq; }
  __syncthreads();
  const float S1 = reds[0] + reds[1] + reds[2] + reds[3];
  const float S2 = reds2[0] + reds2[1] + reds2[2] + reds2[3];
  const float mu = S1 * (1.f / H_);
  const float var = S2 * (1.f / H_) - mu * mu;
  const float rstd = rsqrtf(var + 1e-12f);
  const float4 g = ((const float4*)gamma)[tid];
  const float4 bb = ((const float4*)beta)[tid];
  float4 o;
  o.x = (e0 - mu) * rstd * g.x + bb.x;
  o.y = (e1 - mu) * rstd * g.y + bb.y;
  o.z = (e2 - mu) * rstd * g.z + bb.z;
  o.w = (e3 - mu) * rstd * g.w + bb.w;
  ((float4*)(out + ((size_t)row << 10)))[tid] = o;
}

extern "C" void kernel_launch(void* const* d_in, const int* in_sizes, int n_in,
                              void* d_out, int out_size, void* d_ws, size_t ws_size,
                              hipStream_t stream) {
  const float* X     = (const float*)d_in[0];
  const float* Wq    = (const float*)d_in[1];
  const float* bq    = (const float*)d_in[2];
  const float* Wk    = (const float*)d_in[3];
  const float* bk    = (const float*)d_in[4];
  const float* Wv    = (const float*)d_in[5];
  const float* bv    = (const float*)d_in[6];
  const float* Wo    = (const float*)d_in[7];
  const float* bo    = (const float*)d_in[8];
  const float* gamma = (const float*)d_in[9];
  const float* beta  = (const float*)d_in[10];
  float* out = (float*)d_out;

  const size_t T = (size_t)M_ * H_;  // 4M floats = 16 MB
  float* Qb = (float*)d_ws;
  float* Kb = Qb + T;
  float* Vb = Kb + T;
  float* ctx  = Qb;  // attention writes ctx in-place over Q
  float* attn = Kb;  // O-proj output overwrites K (no longer needed)

  dim3 grid(H_ / 64, M_ / 64), blk(256);
  hipLaunchKernelGGL((gemm_bias<false, true>), grid, blk, 0, stream, X, Wq, bq, Qb);
  hipLaunchKernelGGL((gemm_bias<false, true>), grid, blk, 0, stream, X, Wk, bk, Kb);
  hipLaunchKernelGGL((gemm_bias<false, true>), grid, blk, 0, stream, X, Wv, bv, Vb);
  hipLaunchKernelGGL(attn_kernel, dim3(B_ * NH_ * S_), blk, 0, stream, Qb, Kb, Vb, ctx);
  hipLaunchKernelGGL((gemm_bias<true, false>), grid, blk, 0, stream, ctx, Wo, bo, attn);
  hipLaunchKernelGGL(resid_ln, dim3(M_), blk, 0, stream, attn, X, gamma, beta, out);
}

// Round 3
// 759.197 us; speedup vs baseline: 8.3568x; 8.3568x over previous
//
#include <hip/hip_runtime.h>
#include <hip/hip_bf16.h>

#define B_ 2
#define S_ 2048
#define H_ 1024
#define NH_ 16
#define HD_ 64
#define M_ (B_*S_)   // 4096 rows

typedef __attribute__((ext_vector_type(8))) short bf16x8;
typedef __attribute__((ext_vector_type(4))) float f32x4;

// ---------------- helpers ----------------
__device__ inline float waveReduceSum(float v) {
#pragma unroll
  for (int off = 32; off >= 1; off >>= 1) v += __shfl_xor(v, off);
  return v;
}

__device__ inline short f2bf(float f) {
  union { float f; unsigned u; } v; v.f = f;
  unsigned r = v.u + 0x7fffu + ((v.u >> 16) & 1u);  // RNE
  return (short)(r >> 16);
}

__device__ inline bf16x8 pack8(float4 a, float4 b) {
  bf16x8 r;
  r[0] = f2bf(a.x); r[1] = f2bf(a.y); r[2] = f2bf(a.z); r[3] = f2bf(a.w);
  r[4] = f2bf(b.x); r[5] = f2bf(b.y); r[6] = f2bf(b.z); r[7] = f2bf(b.w);
  return r;
}

// ---------------- GEMM: C[M,1024] = A[M,1024] @ W[1024,1024] + bias ----------------
template<bool HEAD_IN, bool HEAD_OUT>
__global__ __launch_bounds__(256)
void gemm_bias(const float* __restrict__ A, const float* __restrict__ W,
               const float* __restrict__ bias, float* __restrict__ C) {
  const int K = H_, N = H_;
  __shared__ float As[64][20];
  __shared__ float Bs[16][68];

  const int tid = threadIdx.x;
  const int tx = tid & 15, ty = tid >> 4;
  const int m0 = blockIdx.y * 64, n0 = blockIdx.x * 64;

  const int lr = tid >> 2;
  const int lk = (tid & 3) << 2;
  const int bk = tid >> 4;
  const int bn = (tid & 15) << 2;

  float acc[4][4] = {};

  for (int k0 = 0; k0 < K; k0 += 16) {
    float4 av;
    if (!HEAD_IN) {
      av = *(const float4*)(A + (size_t)(m0 + lr) * K + (k0 + lk));
    } else {
      int m = m0 + lr, k = k0 + lk;
      int b = m >> 11, s = m & (S_ - 1);
      int h = k >> 6,  d = k & 63;
      av = *(const float4*)(A + (((size_t)(b * NH_ + h) * S_ + s) << 6) + d);
    }
    float4 bv = *(const float4*)(W + (size_t)(k0 + bk) * N + (n0 + bn));

    __syncthreads();
    *(float4*)&As[lr][lk] = av;
    *(float4*)&Bs[bk][bn] = bv;
    __syncthreads();

#pragma unroll
    for (int kk = 0; kk < 16; ++kk) {
      float a[4], b[4];
#pragma unroll
      for (int i = 0; i < 4; ++i) a[i] = As[4 * ty + i][kk];
#pragma unroll
      for (int j = 0; j < 4; ++j) b[j] = Bs[kk][4 * tx + j];
#pragma unroll
      for (int i = 0; i < 4; ++i)
#pragma unroll
        for (int j = 0; j < 4; ++j)
          acc[i][j] += a[i] * b[j];
    }
  }

#pragma unroll
  for (int i = 0; i < 4; ++i) {
    int m = m0 + 4 * ty + i;
#pragma unroll
    for (int j = 0; j < 4; ++j) {
      int n = n0 + 4 * tx + j;
      float v = acc[i][j] + bias[n];
      if (!HEAD_OUT) {
        C[(size_t)m * N + n] = v;
      } else {
        int b = m >> 11, s = m & (S_ - 1);
        int h = n >> 6,  d = n & 63;
        C[(((size_t)(b * NH_ + h) * S_ + s) << 6) + d] = v;
      }
    }
  }
}

// ---------------- Flash attention, bf16 MFMA ----------------
// Q,K,V fp32 in [B*NH, S, 64]; ctx fp32 written over Q (each block touches only
// its own 64 q-rows, which it has fully consumed into registers first).
// Block = 4 waves; wave w owns q-rows [q0+16w, q0+16w+16). KV tiles of 64.
#define KVB 64
#define LDK 72  // padded row length (bf16 elems): 144B stride breaks 32-bank alias

__global__ __launch_bounds__(256)
void attn_mfma(const float* __restrict__ Qg, const float* __restrict__ Kg,
               const float* __restrict__ Vg, float* __restrict__ ctx) {
  __shared__ short K_lds[KVB][LDK];
  __shared__ short V_lds[KVB][LDK];
  __shared__ short P_lds[4][16][LDK];

  const int tid  = threadIdx.x;
  const int lane = tid & 63;
  const int wv   = tid >> 6;
  const int l16  = lane & 15, lg = lane >> 4;

  const int qb = blockIdx.x;   // 0..31 (q block of 64)
  const int bh = blockIdx.y;   // 0..31 (b*NH+h)
  const float* Qh = Qg + ((size_t)bh * S_ << 6);
  const float* Kh = Kg + ((size_t)bh * S_ << 6);
  const float* Vh = Vg + ((size_t)bh * S_ << 6);

  const int q0 = qb * 64 + wv * 16;

  // Q fragments for 2 k-steps (d = 8*lg + 32*ks + j), scale 1/sqrt(64) folded in
  bf16x8 qf[2];
  {
    const float* qr = Qh + ((size_t)(q0 + l16) << 6) + lg * 8;
#pragma unroll
    for (int ks = 0; ks < 2; ++ks) {
      float4 a = *(const float4*)(qr + 32 * ks);
      float4 b = *(const float4*)(qr + 32 * ks + 4);
      a.x *= 0.125f; a.y *= 0.125f; a.z *= 0.125f; a.w *= 0.125f;
      b.x *= 0.125f; b.y *= 0.125f; b.z *= 0.125f; b.w *= 0.125f;
      qf[ks] = pack8(a, b);
    }
  }

  // staging mapping: thread -> K/V row (tid>>2), 16 d's at (tid&3)*16
  const int kr = tid >> 2;
  const int d0s = (tid & 3) << 4;

  f32x4 o[4] = {};            // ctx acc: row q0+4*lg+r, col 16t+l16
  float m_run[4], l_run[4];
#pragma unroll
  for (int r = 0; r < 4; ++r) { m_run[r] = -1e30f; l_run[r] = 0.f; }

  for (int kv0 = 0; kv0 < S_; kv0 += KVB) {
    __syncthreads();  // previous tile fully consumed
    {
      const float* ks_ = Kh + ((size_t)(kv0 + kr) << 6) + d0s;
      const float* vs_ = Vh + ((size_t)(kv0 + kr) << 6) + d0s;
      float4 k0 = ((const float4*)ks_)[0], k1 = ((const float4*)ks_)[1];
      float4 k2 = ((const float4*)ks_)[2], k3 = ((const float4*)ks_)[3];
      float4 v0 = ((const float4*)vs_)[0], v1 = ((const float4*)vs_)[1];
      float4 v2 = ((const float4*)vs_)[2], v3 = ((const float4*)vs_)[3];
      *(bf16x8*)&K_lds[kr][d0s]     = pack8(k0, k1);
      *(bf16x8*)&K_lds[kr][d0s + 8] = pack8(k2, k3);
      *(bf16x8*)&V_lds[kr][d0s]     = pack8(v0, v1);
      *(bf16x8*)&V_lds[kr][d0s + 8] = pack8(v2, v3);
    }
    __syncthreads();

    // QK^T: s[t] covers cols kv = 16t+l16, rows q = 4*lg+r
    f32x4 s[4] = {};
#pragma unroll
    for (int ks = 0; ks < 2; ++ks)
#pragma unroll
      for (int t = 0; t < 4; ++t) {
        bf16x8 kf = *(const bf16x8*)&K_lds[t * 16 + l16][8 * lg + 32 * ks];
        s[t] = __builtin_amdgcn_mfma_f32_16x16x32_bf16(qf[ks], kf, s[t], 0, 0, 0);
      }

    // online softmax (row stats across the 16-lane group)
    float pm[4];
#pragma unroll
    for (int r = 0; r < 4; ++r) {
      float m0 = fmaxf(fmaxf(s[0][r], s[1][r]), fmaxf(s[2][r], s[3][r]));
#pragma unroll
      for (int off = 1; off < 16; off <<= 1) m0 = fmaxf(m0, __shfl_xor(m0, off));
      pm[r] = m0;
    }
    float scl[4], rs[4];
#pragma unroll
    for (int r = 0; r < 4; ++r) {
      float mn = fmaxf(m_run[r], pm[r]);
      scl[r] = __expf(m_run[r] - mn);
      m_run[r] = mn;
      rs[r] = 0.f;
    }
#pragma unroll
    for (int t = 0; t < 4; ++t)
#pragma unroll
      for (int r = 0; r < 4; ++r) {
        float p = __expf(s[t][r] - m_run[r]);
        rs[r] += p;
        P_lds[wv][4 * lg + r][16 * t + l16] = f2bf(p);
      }
#pragma unroll
    for (int r = 0; r < 4; ++r) {
      float sm = rs[r];
#pragma unroll
      for (int off = 1; off < 16; off <<= 1) sm += __shfl_xor(sm, off);
      l_run[r] = l_run[r] * scl[r] + sm;
#pragma unroll
      for (int t = 0; t < 4; ++t) o[t][r] *= scl[r];
    }

    // PV: A = P (from P_lds), B = V (scalar transpose-reads from V_lds)
#pragma unroll
    for (int ks = 0; ks < 2; ++ks) {
      bf16x8 pf = *(const bf16x8*)&P_lds[wv][l16][8 * lg + 32 * ks];
#pragma unroll
      for (int t = 0; t < 4; ++t) {
        bf16x8 vf;
#pragma unroll
        for (int j = 0; j < 8; ++j)
          vf[j] = V_lds[8 * lg + 32 * ks + j][16 * t + l16];
        o[t] = __builtin_amdgcn_mfma_f32_16x16x32_bf16(pf, vf, o[t], 0, 0, 0);
      }
    }
  }

  // epilogue: normalize and store fp32 ctx
#pragma unroll
  for (int t = 0; t < 4; ++t)
#pragma unroll
    for (int r = 0; r < 4; ++r)
      ctx[(((size_t)bh * S_ + (q0 + 4 * lg + r)) << 6) + 16 * t + l16] =
          o[t][r] / l_run[r];
}

// ---------------- residual + LayerNorm ----------------
__global__ __launch_bounds__(256)
void resid_ln(const float* __restrict__ attn_out, const float* __restrict__ hs,
              const float* __restrict__ gamma, const float* __restrict__ beta,
              float* __restrict__ out) {
  __shared__ float reds[4], reds2[4];
  const int row = blockIdx.x;
  const int tid = threadIdx.x;
  const float4* a4 = (const float4*)(attn_out + ((size_t)row << 10));
  const float4* h4 = (const float4*)(hs + ((size_t)row << 10));
  float4 a = a4[tid], h = h4[tid];
  float e0 = a.x + h.x, e1 = a.y + h.y, e2 = a.z + h.z, e3 = a.w + h.w;
  float s  = e0 + e1 + e2 + e3;
  float sq = e0 * e0 + e1 * e1 + e2 * e2 + e3 * e3;
  s = waveReduceSum(s);
  sq = waveReduceSum(sq);
  const int lane = tid & 63, wave = tid >> 6;
  if (lane == 0) { reds[wave] = s; reds2[wave] = sq; }
  __syncthreads();
  const float S1 = reds[0] + reds[1] + reds[2] + reds[3];
  const float S2 = reds2[0] + reds2[1] + reds2[2] + reds2[3];
  const float mu = S1 * (1.f / H_);
  const float var = S2 * (1.f / H_) - mu * mu;
  const float rstd = rsqrtf(var + 1e-12f);
  const float4 g = ((const float4*)gamma)[tid];
  const float4 bb = ((const float4*)beta)[tid];
  float4 o;
  o.x = (e0 - mu) * rstd * g.x + bb.x;
  o.y = (e1 - mu) * rstd * g.y + bb.y;
  o.z = (e2 - mu) * rstd * g.z + bb.z;
  o.w = (e3 - mu) * rstd * g.w + bb.w;
  ((float4*)(out + ((size_t)row << 10)))[tid] = o;
}

extern "C" void kernel_launch(void* const* d_in, const int* in_sizes, int n_in,
                              void* d_out, int out_size, void* d_ws, size_t ws_size,
                              hipStream_t stream) {
  const float* X     = (const float*)d_in[0];
  const float* Wq    = (const float*)d_in[1];
  const float* bq    = (const float*)d_in[2];
  const float* Wk    = (const float*)d_in[3];
  const float* bk    = (const float*)d_in[4];
  const float* Wv    = (const float*)d_in[5];
  const float* bv    = (const float*)d_in[6];
  const float* Wo    = (const float*)d_in[7];
  const float* bo    = (const float*)d_in[8];
  const float* gamma = (const float*)d_in[9];
  const float* beta  = (const float*)d_in[10];
  float* out = (float*)d_out;

  const size_t T = (size_t)M_ * H_;  // 16 MB fp32
  float* Qb = (float*)d_ws;
  float* Kb = Qb + T;
  float* Vb = Kb + T;
  float* ctx  = Qb;  // attention writes ctx in-place over Q (row-local)
  float* attn = Kb;  // O-proj output overwrites K

  dim3 grid(H_ / 64, M_ / 64), blk(256);
  hipLaunchKernelGGL((gemm_bias<false, true>), grid, blk, 0, stream, X, Wq, bq, Qb);
  hipLaunchKernelGGL((gemm_bias<false, true>), grid, blk, 0, stream, X, Wk, bk, Kb);
  hipLaunchKernelGGL((gemm_bias<false, true>), grid, blk, 0, stream, X, Wv, bv, Vb);
  hipLaunchKernelGGL(attn_mfma, dim3(S_ / 64, B_ * NH_), blk, 0, stream, Qb, Kb, Vb, ctx);
  hipLaunchKernelGGL((gemm_bias<true, false>), grid, blk, 0, stream, ctx, Wo, bo, attn);
  hipLaunchKernelGGL(resid_ln, dim3(M_), blk, 0, stream, attn, X, gamma, beta, out);
}

// Round 4
// 342.515 us; speedup vs baseline: 18.5232x; 2.2165x over previous
//
#include <hip/hip_runtime.h>
#include <hip/hip_bf16.h>

#define B_ 2
#define S_ 2048
#define H_ 1024
#define NH_ 16
#define HD_ 64
#define M_ (B_*S_)   // 4096 rows

typedef __attribute__((ext_vector_type(8))) short bf16x8;
typedef __attribute__((ext_vector_type(4))) short bf16x4;
typedef __attribute__((ext_vector_type(4))) float f32x4;

// ---------------- helpers ----------------
__device__ inline float waveReduceSum(float v) {
#pragma unroll
  for (int off = 32; off >= 1; off >>= 1) v += __shfl_xor(v, off);
  return v;
}

__device__ inline short f2bf(float f) {
  union { float f; unsigned u; } v; v.f = f;
  unsigned r = v.u + 0x7fffu + ((v.u >> 16) & 1u);  // RNE
  return (short)(r >> 16);
}

__device__ inline void async_load16(const void* g, void* l) {
  __builtin_amdgcn_global_load_lds(
      (const __attribute__((address_space(1))) void*)g,
      (__attribute__((address_space(3))) void*)l, 16, 0, 0);
}

// ---------------- fp32 -> bf16 convert (X) ----------------
__global__ __launch_bounds__(256)
void cvt_bf16(const float* __restrict__ in, short* __restrict__ out) {
  const size_t i = (size_t)blockIdx.x * 256 + threadIdx.x;
  float4 v = ((const float4*)in)[i];
  bf16x4 o;
  o[0] = f2bf(v.x); o[1] = f2bf(v.y); o[2] = f2bf(v.z); o[3] = f2bf(v.w);
  ((bf16x4*)out)[i] = o;
}

// ---------------- W[k][n] fp32 -> Wt[n][k] bf16, 4 matrices ----------------
__global__ __launch_bounds__(256)
void transpose_w4(const float* __restrict__ W0, const float* __restrict__ W1,
                  const float* __restrict__ W2, const float* __restrict__ W3,
                  short* __restrict__ T0, short* __restrict__ T1,
                  short* __restrict__ T2, short* __restrict__ T3) {
  const float* W; short* T;
  switch (blockIdx.z) {
    case 0: W = W0; T = T0; break;
    case 1: W = W1; T = T1; break;
    case 2: W = W2; T = T2; break;
    default: W = W3; T = T3; break;
  }
  __shared__ float tile[32][36];
  const int tid = threadIdx.x;
  const int tx = tid & 7, ty = tid >> 3;       // tx: col-group of 4, ty: row 0..31
  const int k0 = blockIdx.y << 5, n0 = blockIdx.x << 5;
  float4 v = *(const float4*)&W[(size_t)(k0 + ty) * H_ + n0 + (tx << 2)];
  tile[ty][(tx << 2) + 0] = v.x;
  tile[ty][(tx << 2) + 1] = v.y;
  tile[ty][(tx << 2) + 2] = v.z;
  tile[ty][(tx << 2) + 3] = v.w;
  __syncthreads();
  bf16x4 o;
  o[0] = f2bf(tile[(tx << 2) + 0][ty]);
  o[1] = f2bf(tile[(tx << 2) + 1][ty]);
  o[2] = f2bf(tile[(tx << 2) + 2][ty]);
  o[3] = f2bf(tile[(tx << 2) + 3][ty]);
  *(bf16x4*)&T[(size_t)(n0 + ty) * H_ + k0 + (tx << 2)] = o;
}

// ---------------- bf16 MFMA GEMM: C[M,1024] = A[M,1024] @ Bt^T + bias ----------------
// A bf16 [M][1024]; Bt bf16 [1024][1024] with Bt[n][k]; 128x128 tile, BK=32,
// 4 waves (2x2 of 64x64), global_load_lds width-16 staging, 2-phase dbuf.
// OUT_MODE 0: fp32 flat [M][1024]. OUT_MODE 1: bf16 head layout [B,NH,S,HD].
template<int OUT_MODE>
__global__ __launch_bounds__(256)
void gemm_bf16(const short* __restrict__ A, const short* __restrict__ Bt,
               const float* __restrict__ bias, void* __restrict__ Cout) {
  __shared__ short A_lds[2][128][32];   // 8 KB per buf
  __shared__ short B_lds[2][128][32];
  const int tid = threadIdx.x;
  const int lane = tid & 63, wv = tid >> 6;
  const int l16 = lane & 15, lg = lane >> 4;
  const int wr = wv >> 1, wc = wv & 1;
  const int m0 = blockIdx.y << 7, n0 = blockIdx.x << 7;
  const int K = H_;

  // staging: wave wv issues chunks c = 2wv, 2wv+1 (16 rows x 32 k each = 1024B)
  // lane -> row 16c + (lane>>2), k-short offset (lane&3)*8  (matches dest base+lane*16)
  const int srow = lane >> 2, soff = (lane & 3) << 3;

  f32x4 acc[4][4] = {};

  // prologue: stage k-tile 0 into buf 0
#pragma unroll
  for (int i = 0; i < 2; ++i) {
    const int c = 2 * wv + i;
    async_load16(A + (size_t)(m0 + 16 * c + srow) * K + soff, &A_lds[0][16 * c][0]);
    async_load16(Bt + (size_t)(n0 + 16 * c + srow) * K + soff, &B_lds[0][16 * c][0]);
  }

  int cur = 0;
  for (int t = 0; t < K / 32; ++t) {
    __syncthreads();  // drains vmcnt: buf[cur] ready; buf[cur^1] readers done
    if (t + 1 < K / 32) {
      const int k0 = (t + 1) << 5;
#pragma unroll
      for (int i = 0; i < 2; ++i) {
        const int c = 2 * wv + i;
        async_load16(A + (size_t)(m0 + 16 * c + srow) * K + k0 + soff,
                     &A_lds[cur ^ 1][16 * c][0]);
        async_load16(Bt + (size_t)(n0 + 16 * c + srow) * K + k0 + soff,
                     &B_lds[cur ^ 1][16 * c][0]);
      }
    }
    bf16x8 af[4], bf[4];
#pragma unroll
    for (int i = 0; i < 4; ++i)
      af[i] = *(const bf16x8*)&A_lds[cur][64 * wr + 16 * i + l16][8 * lg];
#pragma unroll
    for (int j = 0; j < 4; ++j)
      bf[j] = *(const bf16x8*)&B_lds[cur][64 * wc + 16 * j + l16][8 * lg];
#pragma unroll
    for (int i = 0; i < 4; ++i)
#pragma unroll
      for (int j = 0; j < 4; ++j)
        acc[i][j] = __builtin_amdgcn_mfma_f32_16x16x32_bf16(af[i], bf[j], acc[i][j], 0, 0, 0);
    cur ^= 1;
  }

#pragma unroll
  for (int i = 0; i < 4; ++i) {
#pragma unroll
    for (int j = 0; j < 4; ++j) {
      const int n = n0 + 64 * wc + 16 * j + l16;
      const float bv = bias[n];
#pragma unroll
      for (int r = 0; r < 4; ++r) {
        const int m = m0 + 64 * wr + 16 * i + 4 * lg + r;
        const float val = acc[i][j][r] + bv;
        if (OUT_MODE == 0) {
          ((float*)Cout)[(size_t)m * H_ + n] = val;
        } else {
          const int b = m >> 11, s = m & (S_ - 1);
          const int h = n >> 6, d = n & 63;
          ((short*)Cout)[(((size_t)(b * NH_ + h) * S_ + s) << 6) + d] = f2bf(val);
        }
      }
    }
  }
}

// ---------------- Flash attention, bf16 in / bf16 out ----------------
// Q,K,V bf16 [B*NH, S, 64]; ctx bf16 [B, S, H] (= [B,S,NH,HD] flat).
// Block = 4 waves; wave w owns q-rows [q0+16w, q0+16w+16). KV tiles of 64,
// reg-staged double-buffer; V stored transposed in LDS for vector PV reads.
#define KVB 64
#define LDK 72  // padded row (bf16): 144B stride -> <=2-way conflicts on b128 reads

__global__ __launch_bounds__(256)
void attn_mfma(const short* __restrict__ Qg, const short* __restrict__ Kg,
               const short* __restrict__ Vg, short* __restrict__ ctxb) {
  __shared__ short K_lds[2][KVB][LDK];   // [kv][d]
  __shared__ short V_t[2][KVB][LDK];     // [d][kv]  (transposed)
  __shared__ short P_lds[4][16][LDK];

  const int tid  = threadIdx.x;
  const int lane = tid & 63;
  const int wv   = tid >> 6;
  const int l16  = lane & 15, lg = lane >> 4;

  const int qb = blockIdx.x;
  const int bh = blockIdx.y;
  const short* Qh = Qg + ((size_t)bh * S_ << 6);
  const short* Kh = Kg + ((size_t)bh * S_ << 6);
  const short* Vh = Vg + ((size_t)bh * S_ << 6);

  const int q0 = qb * 64 + wv * 16;

  bf16x8 qf[2];
  qf[0] = *(const bf16x8*)&Qh[((size_t)(q0 + l16) << 6) + 8 * lg];
  qf[1] = *(const bf16x8*)&Qh[((size_t)(q0 + l16) << 6) + 8 * lg + 32];

  const int kr = tid >> 2, d0 = (tid & 3) << 4;

  f32x4 o[4] = {};
  float m_run[4], l_run[4];
#pragma unroll
  for (int r = 0; r < 4; ++r) { m_run[r] = -1e30f; l_run[r] = 0.f; }

  // prologue: stage tile 0 into buf 0
  {
    bf16x8 ka = *(const bf16x8*)&Kh[((size_t)kr << 6) + d0];
    bf16x8 kb = *(const bf16x8*)&Kh[((size_t)kr << 6) + d0 + 8];
    bf16x8 va = *(const bf16x8*)&Vh[((size_t)kr << 6) + d0];
    bf16x8 vb = *(const bf16x8*)&Vh[((size_t)kr << 6) + d0 + 8];
    *(bf16x8*)&K_lds[0][kr][d0] = ka;
    *(bf16x8*)&K_lds[0][kr][d0 + 8] = kb;
#pragma unroll
    for (int j = 0; j < 8; ++j) {
      V_t[0][d0 + j][kr] = va[j];
      V_t[0][d0 + 8 + j][kr] = vb[j];
    }
  }

  int cur = 0;
  for (int t = 0; t < S_ / KVB; ++t) {
    // issue next-tile global loads early (latency hides under compute)
    bf16x8 nka, nkb, nva, nvb;
    const bool pre = (t + 1 < S_ / KVB);
    if (pre) {
      const size_t nb = (size_t)((t + 1) * KVB + kr) << 6;
      nka = *(const bf16x8*)&Kh[nb + d0];
      nkb = *(const bf16x8*)&Kh[nb + d0 + 8];
      nva = *(const bf16x8*)&Vh[nb + d0];
      nvb = *(const bf16x8*)&Vh[nb + d0 + 8];
    }
    __syncthreads();  // buf[cur] writes (from prev iter) visible

    // QK^T: s[tt] covers cols kv = 16tt+l16, rows q = 4lg+r
    f32x4 s[4] = {};
#pragma unroll
    for (int ks = 0; ks < 2; ++ks)
#pragma unroll
      for (int tt = 0; tt < 4; ++tt) {
        bf16x8 kf = *(const bf16x8*)&K_lds[cur][tt * 16 + l16][8 * lg + 32 * ks];
        s[tt] = __builtin_amdgcn_mfma_f32_16x16x32_bf16(qf[ks], kf, s[tt], 0, 0, 0);
      }
#pragma unroll
    for (int tt = 0; tt < 4; ++tt) s[tt] *= 0.125f;  // 1/sqrt(64)

    // online softmax (row stats across 16-lane group)
    float pm[4];
#pragma unroll
    for (int r = 0; r < 4; ++r) {
      float m0 = fmaxf(fmaxf(s[0][r], s[1][r]), fmaxf(s[2][r], s[3][r]));
#pragma unroll
      for (int off = 1; off < 16; off <<= 1) m0 = fmaxf(m0, __shfl_xor(m0, off));
      pm[r] = m0;
    }
    float scl[4], rs[4];
#pragma unroll
    for (int r = 0; r < 4; ++r) {
      float mn = fmaxf(m_run[r], pm[r]);
      scl[r] = __expf(m_run[r] - mn);
      m_run[r] = mn;
      rs[r] = 0.f;
    }
#pragma unroll
    for (int tt = 0; tt < 4; ++tt)
#pragma unroll
      for (int r = 0; r < 4; ++r) {
        float p = __expf(s[tt][r] - m_run[r]);
        rs[r] += p;
        P_lds[wv][4 * lg + r][16 * tt + l16] = f2bf(p);
      }
#pragma unroll
    for (int r = 0; r < 4; ++r) {
      float sm = rs[r];
#pragma unroll
      for (int off = 1; off < 16; off <<= 1) sm += __shfl_xor(sm, off);
      l_run[r] = l_run[r] * scl[r] + sm;
#pragma unroll
      for (int tt = 0; tt < 4; ++tt) o[tt][r] *= scl[r];
    }

    // PV: A = P, B = V^T rows (contiguous kv) -> vector b128 reads
#pragma unroll
    for (int ks = 0; ks < 2; ++ks) {
      bf16x8 pf = *(const bf16x8*)&P_lds[wv][l16][8 * lg + 32 * ks];
#pragma unroll
      for (int tt = 0; tt < 4; ++tt) {
        bf16x8 vf = *(const bf16x8*)&V_t[cur][16 * tt + l16][8 * lg + 32 * ks];
        o[tt] = __builtin_amdgcn_mfma_f32_16x16x32_bf16(pf, vf, o[tt], 0, 0, 0);
      }
    }

    // write next tile into buf[cur^1] (other waves may still read buf[cur]; safe)
    if (pre) {
      *(bf16x8*)&K_lds[cur ^ 1][kr][d0] = nka;
      *(bf16x8*)&K_lds[cur ^ 1][kr][d0 + 8] = nkb;
#pragma unroll
      for (int j = 0; j < 8; ++j) {
        V_t[cur ^ 1][d0 + j][kr] = nva[j];
        V_t[cur ^ 1][d0 + 8 + j][kr] = nvb[j];
      }
    }
    cur ^= 1;
  }

  // epilogue: ctx[b][s][h*64+d] bf16
  const int b = bh >> 4, h = bh & 15;
#pragma unroll
  for (int r = 0; r < 4; ++r) {
    const float inv = 1.f / l_run[r];
    const int q = q0 + 4 * lg + r;
#pragma unroll
    for (int tt = 0; tt < 4; ++tt)
      ctxb[(((size_t)(b * S_ + q) * NH_ + h) << 6) + 16 * tt + l16] =
          f2bf(o[tt][r] * inv);
  }
}

// ---------------- residual + LayerNorm ----------------
__global__ __launch_bounds__(256)
void resid_ln(const float* __restrict__ attn_out, const float* __restrict__ hs,
              const float* __restrict__ gamma, const float* __restrict__ beta,
              float* __restrict__ out) {
  __shared__ float reds[4], reds2[4];
  const int row = blockIdx.x;
  const int tid = threadIdx.x;
  const float4* a4 = (const float4*)(attn_out + ((size_t)row << 10));
  const float4* h4 = (const float4*)(hs + ((size_t)row << 10));
  float4 a = a4[tid], h = h4[tid];
  float e0 = a.x + h.x, e1 = a.y + h.y, e2 = a.z + h.z, e3 = a.w + h.w;
  float s  = e0 + e1 + e2 + e3;
  float sq = e0 * e0 + e1 * e1 + e2 * e2 + e3 * e3;
  s = waveReduceSum(s);
  sq = waveReduceSum(sq);
  const int lane = tid & 63, wave = tid >> 6;
  if (lane == 0) { reds[wave] = s; reds2[wave] = sq; }
  __syncthreads();
  const float S1 = reds[0] + reds[1] + reds[2] + reds[3];
  const float S2 = reds2[0] + reds2[1] + reds2[2] + reds2[3];
  const float mu = S1 * (1.f / H_);
  const float var = S2 * (1.f / H_) - mu * mu;
  const float rstd = rsqrtf(var + 1e-12f);
  const float4 g = ((const float4*)gamma)[tid];
  const float4 bb = ((const float4*)beta)[tid];
  float4 o;
  o.x = (e0 - mu) * rstd * g.x + bb.x;
  o.y = (e1 - mu) * rstd * g.y + bb.y;
  o.z = (e2 - mu) * rstd * g.z + bb.z;
  o.w = (e3 - mu) * rstd * g.w + bb.w;
  ((float4*)(out + ((size_t)row << 10)))[tid] = o;
}

extern "C" void kernel_launch(void* const* d_in, const int* in_sizes, int n_in,
                              void* d_out, int out_size, void* d_ws, size_t ws_size,
                              hipStream_t stream) {
  const float* X     = (const float*)d_in[0];
  const float* Wq    = (const float*)d_in[1];
  const float* bq    = (const float*)d_in[2];
  const float* Wk    = (const float*)d_in[3];
  const float* bk    = (const float*)d_in[4];
  const float* Wv    = (const float*)d_in[5];
  const float* bv    = (const float*)d_in[6];
  const float* Wo    = (const float*)d_in[7];
  const float* bo    = (const float*)d_in[8];
  const float* gamma = (const float*)d_in[9];
  const float* beta  = (const float*)d_in[10];
  float* out = (float*)d_out;

  // workspace layout (peak 40 MB; 48 MB known-available)
  char* ws = (char*)d_ws;
  short* Xbf  = (short*)ws;                        // 8 MB [M][H] bf16
  short* Wtq  = (short*)(ws + ( 8u << 20));        // 2 MB each, Wt[n][k] bf16
  short* Wtk  = (short*)(ws + (10u << 20));
  short* Wtv  = (short*)(ws + (12u << 20));
  short* Wto  = (short*)(ws + (14u << 20));
  short* Qbf  = (short*)(ws + (16u << 20));        // 8 MB head layout bf16
  short* Kbf  = (short*)(ws + (24u << 20));
  short* Vbf  = (short*)(ws + (32u << 20));
  short* ctxb = Xbf;                               // ctx bf16 overwrites Xbf (dead)
  float* attn = (float*)(ws + (16u << 20));        // fp32, overwrites Q/K (dead)

  dim3 blk(256);
  hipLaunchKernelGGL(cvt_bf16, dim3((M_ * H_) / 1024), blk, 0, stream, X, Xbf);
  hipLaunchKernelGGL(transpose_w4, dim3(32, 32, 4), blk, 0, stream,
                     Wq, Wk, Wv, Wo, Wtq, Wtk, Wtv, Wto);
  dim3 gg(H_ / 128, M_ / 128);
  hipLaunchKernelGGL((gemm_bf16<1>), gg, blk, 0, stream, Xbf, Wtq, bq, (void*)Qbf);
  hipLaunchKernelGGL((gemm_bf16<1>), gg, blk, 0, stream, Xbf, Wtk, bk, (void*)Kbf);
  hipLaunchKernelGGL((gemm_bf16<1>), gg, blk, 0, stream, Xbf, Wtv, bv, (void*)Vbf);
  hipLaunchKernelGGL(attn_mfma, dim3(S_ / 64, B_ * NH_), blk, 0, stream,
                     Qbf, Kbf, Vbf, ctxb);
  hipLaunchKernelGGL((gemm_bf16<0>), gg, blk, 0, stream, ctxb, Wto, bo, (void*)attn);
  hipLaunchKernelGGL(resid_ln, dim3(M_), blk, 0, stream, attn, X, gamma, beta, out);
}

// Round 5
// 255.603 us; speedup vs baseline: 24.8215x; 1.3400x over previous
//
#include <hip/hip_runtime.h>
#include <hip/hip_bf16.h>

#define B_ 2
#define S_ 2048
#define H_ 1024
#define NH_ 16
#define HD_ 64
#define M_ (B_*S_)   // 4096 rows

typedef __attribute__((ext_vector_type(8))) short bf16x8;
typedef __attribute__((ext_vector_type(4))) short bf16x4;
typedef __attribute__((ext_vector_type(4))) float f32x4;
typedef __attribute__((ext_vector_type(4))) int   i32x4;

// ---------------- helpers ----------------
__device__ inline float waveReduceSum(float v) {
#pragma unroll
  for (int off = 32; off >= 1; off >>= 1) v += __shfl_xor(v, off);
  return v;
}

__device__ inline short f2bf(float f) {
  union { float f; unsigned u; } v; v.f = f;
  unsigned r = v.u + 0x7fffu + ((v.u >> 16) & 1u);  // RNE
  return (short)(r >> 16);
}

__device__ inline unsigned cvt_pk_bf16(float lo, float hi) {
  unsigned w;
  asm("v_cvt_pk_bf16_f32 %0, %1, %2" : "=v"(w) : "v"(lo), "v"(hi));
  return w;
}

__device__ inline void async_load16(const void* g, void* l) {
  __builtin_amdgcn_global_load_lds(
      (const __attribute__((address_space(1))) void*)g,
      (__attribute__((address_space(3))) void*)l, 16, 0, 0);
}

// ---------------- fp32 -> bf16 convert (X) ----------------
__global__ __launch_bounds__(256)
void cvt_bf16(const float* __restrict__ in, short* __restrict__ out) {
  const size_t i = (size_t)blockIdx.x * 256 + threadIdx.x;
  float4 v = ((const float4*)in)[i];
  bf16x4 o;
  o[0] = f2bf(v.x); o[1] = f2bf(v.y); o[2] = f2bf(v.z); o[3] = f2bf(v.w);
  ((bf16x4*)out)[i] = o;
}

// ---------------- W[k][n] fp32 -> Wt[n][k] bf16 (QKV packed + O) ----------------
__global__ __launch_bounds__(256)
void transpose_w4(const float* __restrict__ W0, const float* __restrict__ W1,
                  const float* __restrict__ W2, const float* __restrict__ W3,
                  short* __restrict__ Tqkv, short* __restrict__ To) {
  const float* W; short* T;
  switch (blockIdx.z) {
    case 0: W = W0; T = Tqkv; break;
    case 1: W = W1; T = Tqkv + (size_t)1024 * 1024; break;
    case 2: W = W2; T = Tqkv + (size_t)2048 * 1024; break;
    default: W = W3; T = To; break;
  }
  __shared__ float tile[32][36];
  const int tid = threadIdx.x;
  const int tx = tid & 7, ty = tid >> 3;
  const int k0 = blockIdx.y << 5, n0 = blockIdx.x << 5;
  float4 v = *(const float4*)&W[(size_t)(k0 + ty) * H_ + n0 + (tx << 2)];
  tile[ty][(tx << 2) + 0] = v.x;
  tile[ty][(tx << 2) + 1] = v.y;
  tile[ty][(tx << 2) + 2] = v.z;
  tile[ty][(tx << 2) + 3] = v.w;
  __syncthreads();
  bf16x4 o;
  o[0] = f2bf(tile[(tx << 2) + 0][ty]);
  o[1] = f2bf(tile[(tx << 2) + 1][ty]);
  o[2] = f2bf(tile[(tx << 2) + 2][ty]);
  o[3] = f2bf(tile[(tx << 2) + 3][ty]);
  *(bf16x4*)&T[(size_t)(n0 + ty) * H_ + k0 + (tx << 2)] = o;
}

// ---------------- fused QKV GEMM: [4096,1024] @ [1024,3072] ----------------
// A bf16 [M][1024]; Bt bf16 [3072][1024] (row n holds column n of W).
// Q (n<1024): bf16 head layout [bh][s][64], pre-scaled by 0.125.
// K (1024<=n<2048): bf16 head layout [bh][s][64].
// V (n>=2048): bf16 TRANSPOSED [bh][d][S] (b64-packed stores along s).
__global__ __launch_bounds__(256)
void gemm_qkv(const short* __restrict__ A, const short* __restrict__ Bt,
              const float* __restrict__ bq, const float* __restrict__ bk,
              const float* __restrict__ bv, short* __restrict__ Qo,
              short* __restrict__ Ko, short* __restrict__ Vto) {
  __shared__ short A_lds[2][128][32];
  __shared__ short B_lds[2][128][32];
  const int tid = threadIdx.x;
  const int lane = tid & 63, wv = tid >> 6;
  const int l16 = lane & 15, lg = lane >> 4;
  const int wr = wv >> 1, wc = wv & 1;
  // XCD swizzle: 768 blocks, 96 consecutive per XCD (shares A-panels in L2)
  const int swzb = (blockIdx.x & 7) * 96 + (blockIdx.x >> 3);
  const int bx = swzb % 24, by = swzb / 24;
  const int m0 = by << 7, n0 = bx << 7;
  const int K = H_;

  const int srow = lane >> 2, soff = (lane & 3) << 3;

  f32x4 acc[4][4] = {};

#pragma unroll
  for (int i = 0; i < 2; ++i) {
    const int c = 2 * wv + i;
    async_load16(A + (size_t)(m0 + 16 * c + srow) * K + soff, &A_lds[0][16 * c][0]);
    async_load16(Bt + (size_t)(n0 + 16 * c + srow) * K + soff, &B_lds[0][16 * c][0]);
  }

  int cur = 0;
  for (int t = 0; t < K / 32; ++t) {
    __syncthreads();
    if (t + 1 < K / 32) {
      const int k0 = (t + 1) << 5;
#pragma unroll
      for (int i = 0; i < 2; ++i) {
        const int c = 2 * wv + i;
        async_load16(A + (size_t)(m0 + 16 * c + srow) * K + k0 + soff,
                     &A_lds[cur ^ 1][16 * c][0]);
        async_load16(Bt + (size_t)(n0 + 16 * c + srow) * K + k0 + soff,
                     &B_lds[cur ^ 1][16 * c][0]);
      }
    }
    bf16x8 af[4], bfr[4];
#pragma unroll
    for (int i = 0; i < 4; ++i)
      af[i] = *(const bf16x8*)&A_lds[cur][64 * wr + 16 * i + l16][8 * lg];
#pragma unroll
    for (int j = 0; j < 4; ++j)
      bfr[j] = *(const bf16x8*)&B_lds[cur][64 * wc + 16 * j + l16][8 * lg];
#pragma unroll
    for (int i = 0; i < 4; ++i)
#pragma unroll
      for (int j = 0; j < 4; ++j)
        acc[i][j] = __builtin_amdgcn_mfma_f32_16x16x32_bf16(af[i], bfr[j], acc[i][j], 0, 0, 0);
    cur ^= 1;
  }

  const int mt = n0 >> 10;  // uniform per block: 0=Q 1=K 2=V
  const float* bias = (mt == 0) ? bq : (mt == 1 ? bk : bv);
  const float qs = (mt == 0) ? 0.125f : 1.0f;

  if (mt < 2) {
    short* Out = (mt == 0) ? Qo : Ko;
#pragma unroll
    for (int i = 0; i < 4; ++i) {
#pragma unroll
      for (int j = 0; j < 4; ++j) {
        const int nl = (n0 & 1023) + 64 * wc + 16 * j + l16;
        const float bvl = bias[nl];
        const int h = nl >> 6, d = nl & 63;
#pragma unroll
        for (int r = 0; r < 4; ++r) {
          const int m = m0 + 64 * wr + 16 * i + 4 * lg + r;
          const int b = m >> 11, s = m & (S_ - 1);
          Out[(((size_t)(b * NH_ + h) * S_ + s) << 6) + d] =
              f2bf((acc[i][j][r] + bvl) * qs);
        }
      }
    }
  } else {
#pragma unroll
    for (int i = 0; i < 4; ++i) {
      const int mb = m0 + 64 * wr + 16 * i + 4 * lg;  // r=0..3 consecutive s
      const int b = mb >> 11, s = mb & (S_ - 1);
#pragma unroll
      for (int j = 0; j < 4; ++j) {
        const int nl = (n0 & 1023) + 64 * wc + 16 * j + l16;
        const float bvl = bias[nl];
        const int h = nl >> 6, d = nl & 63;
        bf16x4 pk;
#pragma unroll
        for (int r = 0; r < 4; ++r) pk[r] = f2bf(acc[i][j][r] + bvl);
        *(bf16x4*)&Vto[(((size_t)(b * NH_ + h) * HD_ + d) << 11) + s] = pk;
      }
    }
  }
}

// ---------------- O-projection GEMM: ctx_bf16 [M][1024] @ Wto^T -> fp32 ----------------
__global__ __launch_bounds__(256)
void gemm_o(const short* __restrict__ A, const short* __restrict__ Bt,
            const float* __restrict__ bias, float* __restrict__ C) {
  __shared__ short A_lds[2][128][32];
  __shared__ short B_lds[2][128][32];
  const int tid = threadIdx.x;
  const int lane = tid & 63, wv = tid >> 6;
  const int l16 = lane & 15, lg = lane >> 4;
  const int wr = wv >> 1, wc = wv & 1;
  const int swzb = (blockIdx.x & 7) * 32 + (blockIdx.x >> 3);
  const int bx = swzb & 7, by = swzb >> 3;
  const int m0 = by << 7, n0 = bx << 7;
  const int K = H_;

  const int srow = lane >> 2, soff = (lane & 3) << 3;

  f32x4 acc[4][4] = {};

#pragma unroll
  for (int i = 0; i < 2; ++i) {
    const int c = 2 * wv + i;
    async_load16(A + (size_t)(m0 + 16 * c + srow) * K + soff, &A_lds[0][16 * c][0]);
    async_load16(Bt + (size_t)(n0 + 16 * c + srow) * K + soff, &B_lds[0][16 * c][0]);
  }

  int cur = 0;
  for (int t = 0; t < K / 32; ++t) {
    __syncthreads();
    if (t + 1 < K / 32) {
      const int k0 = (t + 1) << 5;
#pragma unroll
      for (int i = 0; i < 2; ++i) {
        const int c = 2 * wv + i;
        async_load16(A + (size_t)(m0 + 16 * c + srow) * K + k0 + soff,
                     &A_lds[cur ^ 1][16 * c][0]);
        async_load16(Bt + (size_t)(n0 + 16 * c + srow) * K + k0 + soff,
                     &B_lds[cur ^ 1][16 * c][0]);
      }
    }
    bf16x8 af[4], bfr[4];
#pragma unroll
    for (int i = 0; i < 4; ++i)
      af[i] = *(const bf16x8*)&A_lds[cur][64 * wr + 16 * i + l16][8 * lg];
#pragma unroll
    for (int j = 0; j < 4; ++j)
      bfr[j] = *(const bf16x8*)&B_lds[cur][64 * wc + 16 * j + l16][8 * lg];
#pragma unroll
    for (int i = 0; i < 4; ++i)
#pragma unroll
      for (int j = 0; j < 4; ++j)
        acc[i][j] = __builtin_amdgcn_mfma_f32_16x16x32_bf16(af[i], bfr[j], acc[i][j], 0, 0, 0);
    cur ^= 1;
  }

#pragma unroll
  for (int i = 0; i < 4; ++i)
#pragma unroll
    for (int j = 0; j < 4; ++j) {
      const int n = n0 + 64 * wc + 16 * j + l16;
      const float bvl = bias[n];
#pragma unroll
      for (int r = 0; r < 4; ++r) {
        const int m = m0 + 64 * wr + 16 * i + 4 * lg + r;
        C[(size_t)m * H_ + n] = acc[i][j][r] + bvl;
      }
    }
}

// ---------------- Flash attention: swapped QK^T, in-register P ----------------
// Q,K bf16 [bh][s][64] (Q pre-scaled by 0.125); Vt bf16 [bh][d][S];
// ctx bf16 [B,S,NH,HD] flat. Block = 4 waves; wave w: q-rows [q0+16w, +16).
// Swapped QK^T (mfma(K,Q)) + K-row remap rho(tt,l16) makes each lane hold
// exactly its PV A-fragment P values -> no P LDS round-trip, no shuffles.
#define KVB 64
#define LDK 72  // padded row (144B): b128 ops conflict-optimal

__global__ __launch_bounds__(256)
void attn_mfma(const short* __restrict__ Qg, const short* __restrict__ Kg,
               const short* __restrict__ Vtg, short* __restrict__ ctxb) {
  __shared__ short K_lds[2][KVB][LDK];  // [kv][d]
  __shared__ short V_t[2][KVB][LDK];    // [d][kv]  (from global V^T: vector writes)

  const int tid  = threadIdx.x;
  const int lane = tid & 63;
  const int wv   = tid >> 6;
  const int l16  = lane & 15, lg = lane >> 4;

  // XCD swizzle: 1024 blocks -> 128 consecutive per XCD (4 full heads' K/V in L2)
  const int swz = (blockIdx.x & 7) * 128 + (blockIdx.x >> 3);
  const int bh = swz >> 5, qb = swz & 31;

  const short* Qh = Qg + ((size_t)bh * S_ << 6);
  const short* Kh = Kg + ((size_t)bh * S_ << 6);
  const short* Vh = Vtg + ((size_t)bh << 6) * S_;  // [64][2048]

  const int q0 = qb * 64 + wv * 16;

  bf16x8 qf[2];
  qf[0] = *(const bf16x8*)&Qh[((size_t)(q0 + l16) << 6) + 8 * lg];
  qf[1] = *(const bf16x8*)&Qh[((size_t)(q0 + l16) << 6) + 8 * lg + 32];

  const int kr = tid >> 2, d0 = (tid & 3) << 4;     // staging: row tid>>2, 16 cols
  const int l16part = ((l16 >> 2) << 3) + (l16 & 3);  // K-row remap, lane part

  f32x4 o[4] = {};
  float m_run = -1e30f, l_run = 0.f;  // stats for q = l16 (replicated over lg)

  // prologue: stage tile 0 into buf 0
  {
    *(bf16x8*)&K_lds[0][kr][d0]     = *(const bf16x8*)&Kh[((size_t)kr << 6) + d0];
    *(bf16x8*)&K_lds[0][kr][d0 + 8] = *(const bf16x8*)&Kh[((size_t)kr << 6) + d0 + 8];
    *(bf16x8*)&V_t[0][kr][d0]       = *(const bf16x8*)&Vh[(size_t)kr * S_ + d0];
    *(bf16x8*)&V_t[0][kr][d0 + 8]   = *(const bf16x8*)&Vh[(size_t)kr * S_ + d0 + 8];
  }

  int cur = 0;
  for (int t = 0; t < S_ / KVB; ++t) {
    bf16x8 nk0, nk1, nv0, nv1;
    const bool pre = (t + 1 < S_ / KVB);
    if (pre) {
      const size_t kb = (size_t)((t + 1) * KVB + kr) << 6;
      nk0 = *(const bf16x8*)&Kh[kb + d0];
      nk1 = *(const bf16x8*)&Kh[kb + d0 + 8];
      const size_t vb = (size_t)kr * S_ + (t + 1) * KVB;
      nv0 = *(const bf16x8*)&Vh[vb + d0];
      nv1 = *(const bf16x8*)&Vh[vb + d0 + 8];
    }
    __syncthreads();

    // swapped QK^T with row-remap: s[tt] row r holds
    // P_raw[kv = 32*(tt>>1) + 8*lg + 4*(tt&1) + r][q = l16]
    f32x4 s[4] = {};
#pragma unroll
    for (int ks = 0; ks < 2; ++ks)
#pragma unroll
      for (int tt = 0; tt < 4; ++tt) {
        const int krow = ((tt >> 1) << 5) + ((tt & 1) << 2) + l16part;
        bf16x8 kf = *(const bf16x8*)&K_lds[cur][krow][8 * lg + 32 * ks];
        s[tt] = __builtin_amdgcn_mfma_f32_16x16x32_bf16(kf, qf[ks], s[tt], 0, 0, 0);
      }

    // tile max for q=l16: in-lane 16 + xor over lanes 16,32
    float pmax = fmaxf(fmaxf(fmaxf(s[0][0], s[0][1]), fmaxf(s[0][2], s[0][3])),
                       fmaxf(fmaxf(s[1][0], s[1][1]), fmaxf(s[1][2], s[1][3])));
    pmax = fmaxf(pmax,
                 fmaxf(fmaxf(fmaxf(s[2][0], s[2][1]), fmaxf(s[2][2], s[2][3])),
                       fmaxf(fmaxf(s[3][0], s[3][1]), fmaxf(s[3][2], s[3][3]))));
    pmax = fmaxf(pmax, __shfl_xor(pmax, 16));
    pmax = fmaxf(pmax, __shfl_xor(pmax, 32));

    const float mn = fmaxf(m_run, pmax);
    const float scl = __expf(m_run - mn);
    m_run = mn;

    float p[4][4];
    float rs = 0.f;
#pragma unroll
    for (int tt = 0; tt < 4; ++tt)
#pragma unroll
      for (int r = 0; r < 4; ++r) {
        p[tt][r] = __expf(s[tt][r] - mn);
        rs += p[tt][r];
      }
    rs += __shfl_xor(rs, 16);
    rs += __shfl_xor(rs, 32);
    l_run = l_run * scl + rs;

    // pack P to bf16 (lane-local PV A-fragments)
    unsigned w[4][2];
#pragma unroll
    for (int tt = 0; tt < 4; ++tt) {
      w[tt][0] = cvt_pk_bf16(p[tt][0], p[tt][1]);
      w[tt][1] = cvt_pk_bf16(p[tt][2], p[tt][3]);
    }

    // gather per-output-row rescale (rows q = 4lg+r; stats live at lane 16lg+4lg+r)
    float sclr[4];
#pragma unroll
    for (int r = 0; r < 4; ++r) sclr[r] = __shfl(scl, 20 * lg + r);
#pragma unroll
    for (int tt = 0; tt < 4; ++tt)
#pragma unroll
      for (int r = 0; r < 4; ++r) o[tt][r] *= sclr[r];

    // PV: A = P (in-register), B = V^T rows (b128 from LDS)
#pragma unroll
    for (int ks = 0; ks < 2; ++ks) {
      i32x4 aw;
      aw[0] = (int)w[2 * ks][0];
      aw[1] = (int)w[2 * ks][1];
      aw[2] = (int)w[2 * ks + 1][0];
      aw[3] = (int)w[2 * ks + 1][1];
      const bf16x8 pf = __builtin_bit_cast(bf16x8, aw);
#pragma unroll
      for (int tt = 0; tt < 4; ++tt) {
        bf16x8 vf = *(const bf16x8*)&V_t[cur][16 * tt + l16][8 * lg + 32 * ks];
        o[tt] = __builtin_amdgcn_mfma_f32_16x16x32_bf16(pf, vf, o[tt], 0, 0, 0);
      }
    }

    if (pre) {
      *(bf16x8*)&K_lds[cur ^ 1][kr][d0]     = nk0;
      *(bf16x8*)&K_lds[cur ^ 1][kr][d0 + 8] = nk1;
      *(bf16x8*)&V_t[cur ^ 1][kr][d0]       = nv0;
      *(bf16x8*)&V_t[cur ^ 1][kr][d0 + 8]   = nv1;
    }
    cur ^= 1;
  }

  // epilogue: ctx[b][s][h*64+d] bf16; rows q = 4lg+r, cols d = 16tt+l16
  float invr[4];
#pragma unroll
  for (int r = 0; r < 4; ++r) invr[r] = 1.f / __shfl(l_run, 20 * lg + r);
  const int b = bh >> 4, h = bh & 15;
#pragma unroll
  for (int r = 0; r < 4; ++r) {
    const int q = q0 + 4 * lg + r;
#pragma unroll
    for (int tt = 0; tt < 4; ++tt)
      ctxb[(((size_t)(b * S_ + q) * NH_ + h) << 6) + 16 * tt + l16] =
          f2bf(o[tt][r] * invr[r]);
  }
}

// ---------------- residual + LayerNorm ----------------
__global__ __launch_bounds__(256)
void resid_ln(const float* __restrict__ attn_out, const float* __restrict__ hs,
              const float* __restrict__ gamma, const float* __restrict__ beta,
              float* __restrict__ out) {
  __shared__ float reds[4], reds2[4];
  const int row = blockIdx.x;
  const int tid = threadIdx.x;
  const float4* a4 = (const float4*)(attn_out + ((size_t)row << 10));
  const float4* h4 = (const float4*)(hs + ((size_t)row << 10));
  float4 a = a4[tid], h = h4[tid];
  float e0 = a.x + h.x, e1 = a.y + h.y, e2 = a.z + h.z, e3 = a.w + h.w;
  float s  = e0 + e1 + e2 + e3;
  float sq = e0 * e0 + e1 * e1 + e2 * e2 + e3 * e3;
  s = waveReduceSum(s);
  sq = waveReduceSum(sq);
  const int lane = tid & 63, wave = tid >> 6;
  if (lane == 0) { reds[wave] = s; reds2[wave] = sq; }
  __syncthreads();
  const float S1 = reds[0] + reds[1] + reds[2] + reds[3];
  const float S2 = reds2[0] + reds2[1] + reds2[2] + reds2[3];
  const float mu = S1 * (1.f / H_);
  const float var = S2 * (1.f / H_) - mu * mu;
  const float rstd = rsqrtf(var + 1e-12f);
  const float4 g = ((const float4*)gamma)[tid];
  const float4 bb = ((const float4*)beta)[tid];
  float4 o;
  o.x = (e0 - mu) * rstd * g.x + bb.x;
  o.y = (e1 - mu) * rstd * g.y + bb.y;
  o.z = (e2 - mu) * rstd * g.z + bb.z;
  o.w = (e3 - mu) * rstd * g.w + bb.w;
  ((float4*)(out + ((size_t)row << 10)))[tid] = o;
}

extern "C" void kernel_launch(void* const* d_in, const int* in_sizes, int n_in,
                              void* d_out, int out_size, void* d_ws, size_t ws_size,
                              hipStream_t stream) {
  const float* X     = (const float*)d_in[0];
  const float* Wq    = (const float*)d_in[1];
  const float* bq    = (const float*)d_in[2];
  const float* Wk    = (const float*)d_in[3];
  const float* bk    = (const float*)d_in[4];
  const float* Wv    = (const float*)d_in[5];
  const float* bv    = (const float*)d_in[6];
  const float* Wo    = (const float*)d_in[7];
  const float* bo    = (const float*)d_in[8];
  const float* gamma = (const float*)d_in[9];
  const float* beta  = (const float*)d_in[10];
  float* out = (float*)d_out;

  // workspace layout (peak 40 MB)
  char* ws = (char*)d_ws;
  short* Xbf  = (short*)ws;                        // 8 MB [M][H] bf16
  short* Wqkv = (short*)(ws + ( 8u << 20));        // 6 MB [3072][1024] bf16
  short* Wto  = (short*)(ws + (14u << 20));        // 2 MB [1024][1024] bf16
  short* Qbf  = (short*)(ws + (16u << 20));        // 8 MB [bh][s][64] (pre-scaled)
  short* Kbf  = (short*)(ws + (24u << 20));        // 8 MB [bh][s][64]
  short* Vt   = (short*)(ws + (32u << 20));        // 8 MB [bh][d][S] (transposed)
  short* ctxb = Xbf;                               // ctx bf16 overwrites Xbf (dead)
  float* attn = (float*)(ws + (16u << 20));        // fp32, overwrites Q/K (dead)

  dim3 blk(256);
  hipLaunchKernelGGL(cvt_bf16, dim3((M_ * H_) / 1024), blk, 0, stream, X, Xbf);
  hipLaunchKernelGGL(transpose_w4, dim3(32, 32, 4), blk, 0, stream,
                     Wq, Wk, Wv, Wo, Wqkv, Wto);
  hipLaunchKernelGGL(gemm_qkv, dim3(768), blk, 0, stream,
                     Xbf, Wqkv, bq, bk, bv, Qbf, Kbf, Vt);
  hipLaunchKernelGGL(attn_mfma, dim3(1024), blk, 0, stream, Qbf, Kbf, Vt, ctxb);
  hipLaunchKernelGGL(gemm_o, dim3(256), blk, 0, stream, ctxb, Wto, bo, attn);
  hipLaunchKernelGGL(resid_ln, dim3(M_), blk, 0, stream, attn, X, gamma, beta, out);
}